// Round 1
// baseline (12519.509 us; speedup 1.0000x reference)
//
#include <hip/hip_runtime.h>
#include <math.h>

#define BATCH 32
#define TLEN  1024
#define DIN   128
#define HID   512
#define NCLS  10
#define TC    128           // time chunk
#define NCHUNK (TLEN/TC)    // 8
#define NSLICE 8            // WGs per batch in recurrence
#define SLICE  64           // output cols per slice WG

// ---------- device-scope atomic helpers (bypass L1/L2 staleness) ----------
__device__ __forceinline__ float agentLoadF(const float* p) {
  return __hip_atomic_load(p, __ATOMIC_RELAXED, __HIP_MEMORY_SCOPE_AGENT);
}
__device__ __forceinline__ void agentStoreF(float* p, float v) {
  __hip_atomic_store(p, v, __ATOMIC_RELAXED, __HIP_MEMORY_SCOPE_AGENT);
}

// ---------- phase A: xw1[t,b,:] = x[b,t,:] @ Wx1 + b1 (one time-chunk) ----------
__global__ __launch_bounds__(256) void k_xw1(
    const float* __restrict__ x, const float* __restrict__ Wx1,
    const float* __restrict__ b1, float* __restrict__ out, int t0)
{
  __shared__ float xst[DIN * 4];           // transposed stage [d][r]
  const int tid  = threadIdx.x;
  const int row0 = blockIdx.x * 4;         // chunk-row = tl*32 + b
  for (int idx = tid; idx < 4 * DIN; idx += 256) {
    int r = idx >> 7, d = idx & (DIN - 1);
    int row = row0 + r;
    int tl = row >> 5, b = row & 31;
    xst[d * 4 + r] = x[((size_t)b * TLEN + (size_t)(t0 + tl)) * DIN + d];
  }
  __syncthreads();
  float acc[4][2];
#pragma unroll
  for (int r = 0; r < 4; ++r) { acc[r][0] = 0.f; acc[r][1] = 0.f; }
  const int j0 = tid, j1 = tid + 256;
  for (int d = 0; d < DIN; ++d) {
    float w0 = Wx1[(size_t)d * HID + j0];
    float w1 = Wx1[(size_t)d * HID + j1];
    float4 xv = *reinterpret_cast<const float4*>(&xst[d * 4]);
    acc[0][0] += xv.x * w0; acc[0][1] += xv.x * w1;
    acc[1][0] += xv.y * w0; acc[1][1] += xv.y * w1;
    acc[2][0] += xv.z * w0; acc[2][1] += xv.z * w1;
    acc[3][0] += xv.w * w0; acc[3][1] += xv.w * w1;
  }
  float bb0 = b1[j0], bb1 = b1[j1];
#pragma unroll
  for (int r = 0; r < 4; ++r) {
    out[(size_t)(row0 + r) * HID + j0] = acc[r][0] + bb0;
    out[(size_t)(row0 + r) * HID + j1] = acc[r][1] + bb1;
  }
}

// ---------- phase C: xw2[row,:] = h1[row,:] @ Wx2 + b2 (one time-chunk) ----------
__global__ __launch_bounds__(256) void k_xw2(
    const float* __restrict__ hin, const float* __restrict__ Wx2,
    const float* __restrict__ b2, float* __restrict__ out)
{
  __shared__ float xst[HID * 8];           // transposed stage [k][r], 16KB
  const int tid  = threadIdx.x;
  const int row0 = blockIdx.x * 8;
  for (int idx = tid; idx < 8 * HID; idx += 256) {
    int r = idx >> 9, k = idx & (HID - 1);
    xst[k * 8 + r] = hin[(size_t)(row0 + r) * HID + k];
  }
  __syncthreads();
  float acc[8][2];
#pragma unroll
  for (int r = 0; r < 8; ++r) { acc[r][0] = 0.f; acc[r][1] = 0.f; }
  const int j0 = tid, j1 = tid + 256;
  for (int k = 0; k < HID; ++k) {
    float w0 = Wx2[(size_t)k * HID + j0];
    float w1 = Wx2[(size_t)k * HID + j1];
    float4 a0 = *reinterpret_cast<const float4*>(&xst[k * 8]);
    float4 a1 = *reinterpret_cast<const float4*>(&xst[k * 8 + 4]);
    float xr[8] = {a0.x, a0.y, a0.z, a0.w, a1.x, a1.y, a1.z, a1.w};
#pragma unroll
    for (int r = 0; r < 8; ++r) { acc[r][0] += xr[r] * w0; acc[r][1] += xr[r] * w1; }
  }
  float bb0 = b2[j0], bb1 = b2[j1];
#pragma unroll
  for (int r = 0; r < 8; ++r) {
    out[(size_t)(row0 + r) * HID + j0] = acc[r][0] + bb0;
    out[(size_t)(row0 + r) * HID + j1] = acc[r][1] + bb1;
  }
}

// ---------- phases B/D: recurrence over one time-chunk ----------
// 256 WGs: wg = b + 32*slice  (peers of batch b share blockIdx%8 -> same XCD
// under round-robin; correctness does not depend on placement).
// Each WG holds Wh[:, slice*64 .. +64) fp32 in LDS (128KB); per step computes
// its 64 outputs, exchanges h through a double-buffered global buffer with a
// monotonic per-batch counter barrier (agent-scope atomics).
__global__ __launch_bounds__(512) void k_recur(
    const float* __restrict__ xw,     // [TC][BATCH][HID] chunk
    const float* __restrict__ Wh,     // [HID][HID]
    float* __restrict__ hout,         // store_all ? [TC][BATCH][HID] : [BATCH][HID]
    float* __restrict__ hbuf,         // [2][BATCH][HID] exchange
    unsigned int* __restrict__ cnt,   // [BATCH] monotonic counters
    int t0, int store_all)
{
  __shared__ float Whs[HID * SLICE];  // [k][j] 128KB
  __shared__ float h_s[HID];
  __shared__ float red[8][SLICE];

  const int tid = threadIdx.x;
  const int wg  = blockIdx.x;
  const int b   = wg & 31;
  const int sl  = wg >> 5;            // 0..7
  const int c0  = sl * SLICE;
  const int j   = tid & 63;
  const int ks  = tid >> 6;           // 0..7 (wave index; k-group)

  // load Wh slice into LDS (once per chunk)
  for (int idx = tid; idx < HID * SLICE; idx += 512) {
    int k = idx >> 6, jj = idx & 63;
    Whs[idx] = Wh[(size_t)k * HID + c0 + jj];
  }
  // initial hidden state
  if (t0 == 0) {
    h_s[tid] = 0.f;
  } else {
    h_s[tid] = agentLoadF(&hbuf[(size_t)(t0 & 1) * (BATCH * HID) + (size_t)b * HID + tid]);
  }
  __syncthreads();

  for (int tl = 0; tl < TC; ++tl) {
    const int gt = t0 + tl;
    // partial dot over own k-group
    float acc = 0.f;
    const int k0 = ks * 64;
#pragma unroll 8
    for (int kk = 0; kk < 64; ++kk) {
      acc += h_s[k0 + kk] * Whs[(k0 + kk) * SLICE + j];
    }
    red[ks][j] = acc;
    __syncthreads();

    if (ks == 0) {  // wave 0 finalizes the 64 outputs of this slice
      float z = xw[((size_t)tl * BATCH + b) * HID + c0 + j];
#pragma unroll
      for (int r = 0; r < 8; ++r) z += red[r][j];
      float hnew = tanhf(z);
      if (store_all) {
        hout[((size_t)tl * BATCH + b) * HID + c0 + j] = hnew;
      } else if (gt == TLEN - 1) {
        hout[(size_t)b * HID + c0 + j] = hnew;
      }
      agentStoreF(&hbuf[(size_t)((gt + 1) & 1) * (BATCH * HID) + (size_t)b * HID + c0 + j], hnew);
    }
    __syncthreads();   // drains vmcnt: all agent stores globally complete here

    if (tid == 0) {
      __hip_atomic_fetch_add(&cnt[b], 1u, __ATOMIC_RELAXED, __HIP_MEMORY_SCOPE_AGENT);
    }
    if (tl == TC - 1) break;   // next chunk's kernel picks up the state

    if (tid == 0) {
      const unsigned target = 8u * (unsigned)(gt + 1);
      while (__hip_atomic_load(&cnt[b], __ATOMIC_RELAXED, __HIP_MEMORY_SCOPE_AGENT) < target) {
        __builtin_amdgcn_s_sleep(1);
      }
      __builtin_amdgcn_fence(__ATOMIC_ACQUIRE, "agent");
    }
    __syncthreads();
    // gather full h for next step (1 value per thread, cache-bypassing)
    h_s[tid] = agentLoadF(&hbuf[(size_t)((gt + 1) & 1) * (BATCH * HID) + (size_t)b * HID + tid]);
    __syncthreads();
  }
}

// ---------- phase E: softmax(h2 @ Wo + bo) ----------
__global__ __launch_bounds__(640) void k_head(
    const float* __restrict__ h2, const float* __restrict__ Wo,
    const float* __restrict__ bo, float* __restrict__ out)
{
  __shared__ float lg[16];
  const int b = blockIdx.x;
  const int c = threadIdx.x >> 6;   // 0..9 (wave per class)
  const int l = threadIdx.x & 63;
  float p = 0.f;
#pragma unroll
  for (int i = 0; i < 8; ++i) {
    int k = l + 64 * i;
    p += h2[(size_t)b * HID + k] * Wo[(size_t)k * NCLS + c];
  }
  for (int off = 32; off; off >>= 1) p += __shfl_down(p, off);
  if (l == 0) lg[c] = p + bo[c];
  __syncthreads();
  if (threadIdx.x == 0) {
    float m = lg[0];
    for (int i = 1; i < NCLS; ++i) m = fmaxf(m, lg[i]);
    float e[NCLS];
    float s = 0.f;
    for (int i = 0; i < NCLS; ++i) { e[i] = expf(lg[i] - m); s += e[i]; }
    for (int i = 0; i < NCLS; ++i) out[(size_t)b * NCLS + i] = e[i] / s;
  }
}

extern "C" void kernel_launch(void* const* d_in, const int* in_sizes, int n_in,
                              void* d_out, int out_size, void* d_ws, size_t ws_size,
                              hipStream_t stream)
{
  (void)in_sizes; (void)n_in; (void)out_size; (void)ws_size;
  const float* x   = (const float*)d_in[0];
  const float* Wx1 = (const float*)d_in[1];
  const float* Wh1 = (const float*)d_in[2];
  const float* b1  = (const float*)d_in[3];
  const float* Wx2 = (const float*)d_in[4];
  const float* Wh2 = (const float*)d_in[5];
  const float* b2  = (const float*)d_in[6];
  const float* Wo  = (const float*)d_in[7];
  const float* bo  = (const float*)d_in[8];
  float* out = (float*)d_out;

  char* ws = (char*)d_ws;
  size_t o = 0;
  const size_t chunkElems = (size_t)TC * BATCH * HID;          // 2M floats, 8MB
  float* bufXW1 = (float*)(ws + o); o += chunkElems * 4;
  float* bufH1  = (float*)(ws + o); o += chunkElems * 4;
  float* bufXW2 = (float*)(ws + o); o += chunkElems * 4;
  float* hbuf1  = (float*)(ws + o); o += (size_t)2 * BATCH * HID * 4;
  float* hbuf2  = (float*)(ws + o); o += (size_t)2 * BATCH * HID * 4;
  float* h2fin  = (float*)(ws + o); o += (size_t)BATCH * HID * 4;
  unsigned int* cnt = (unsigned int*)(ws + o); o += 64 * 4;    // [layer][batch]

  hipMemsetAsync(cnt, 0, 64 * 4, stream);

  for (int c = 0; c < NCHUNK; ++c) {
    const int t0 = c * TC;
    k_xw1<<<(TC * BATCH) / 4, 256, 0, stream>>>(x, Wx1, b1, bufXW1, t0);
    k_recur<<<BATCH * NSLICE, 512, 0, stream>>>(bufXW1, Wh1, bufH1, hbuf1, cnt, t0, 1);
    k_xw2<<<(TC * BATCH) / 8, 256, 0, stream>>>(bufH1, Wx2, b2, bufXW2);
    k_recur<<<BATCH * NSLICE, 512, 0, stream>>>(bufXW2, Wh2, h2fin, hbuf2, cnt + 32, t0, 0);
  }
  k_head<<<BATCH, 640, 0, stream>>>(h2fin, Wo, bo, out);
}

// Round 2
// 2445.196 us; speedup vs baseline: 5.1200x; 5.1200x over previous
//
#include <hip/hip_runtime.h>
#include <hip/hip_fp16.h>
#include <math.h>

#define BATCH 32
#define TLEN  1024
#define DIN   128
#define HID   512
#define NCLS  10
#define NB    2                 // batches per WG
#define NGRP  (BATCH/NB)        // 16 groups
#define NSL   8                 // slice WGs per group per layer (64 cols each)
#define RING  32                // ring depth (slots)
#define SENTV 0xFFFFFFFFu
#define POLL_CAP (1u<<17)

typedef _Float16 hf2 __attribute__((ext_vector_type(2)));

__device__ __forceinline__ unsigned aload(const unsigned* p) {
  return __hip_atomic_load(p, __ATOMIC_RELAXED, __HIP_MEMORY_SCOPE_AGENT);
}
__device__ __forceinline__ void astore(unsigned* p, unsigned v) {
  __hip_atomic_store(p, v, __ATOMIC_RELAXED, __HIP_MEMORY_SCOPE_AGENT);
}
__device__ __forceinline__ int aloadi(const int* p) {
  return __hip_atomic_load(p, __ATOMIC_RELAXED, __HIP_MEMORY_SCOPE_AGENT);
}
__device__ __forceinline__ void astorei(int* p, int v) {
  __hip_atomic_store(p, v, __ATOMIC_RELAXED, __HIP_MEMORY_SCOPE_AGENT);
}

__device__ __forceinline__ float fdot2u(unsigned a, unsigned b, float c) {
#if __has_builtin(__builtin_amdgcn_fdot2)
  return __builtin_amdgcn_fdot2(__builtin_bit_cast(hf2, a),
                                __builtin_bit_cast(hf2, b), c, false);
#else
  hf2 av = __builtin_bit_cast(hf2, a), bv = __builtin_bit_cast(hf2, b);
  return c + (float)av[0] * (float)bv[0] + (float)av[1] * (float)bv[1];
#endif
}

__device__ __forceinline__ unsigned packh2(float lo, float hi) {
  __half2 h = __floats2half2_rn(lo, hi);
  return __builtin_bit_cast(unsigned, h);
}

// ---------- xw1[t,b,:] = x[b,t,:] @ Wx1 + b1, packed f16 pairs, all T ----------
__global__ __launch_bounds__(256) void k_xw1(
    const float* __restrict__ x, const float* __restrict__ Wx1,
    const float* __restrict__ b1, unsigned* __restrict__ xw1)   // [T*B][256] words
{
  __shared__ float xst[DIN * 4];
  const int tid  = threadIdx.x;
  const int row0 = blockIdx.x * 4;            // row = t*32 + b
  for (int idx = tid; idx < 4 * DIN; idx += 256) {
    int r = idx >> 7, d = idx & (DIN - 1);
    int row = row0 + r;
    int t = row >> 5, b = row & 31;
    xst[d * 4 + r] = x[((size_t)b * TLEN + t) * DIN + d];
  }
  __syncthreads();
  float acc[4][2];
#pragma unroll
  for (int r = 0; r < 4; ++r) { acc[r][0] = 0.f; acc[r][1] = 0.f; }
  const int j0 = 2 * tid, j1 = 2 * tid + 1;
  for (int d = 0; d < DIN; ++d) {
    float w0 = Wx1[(size_t)d * HID + j0];
    float w1 = Wx1[(size_t)d * HID + j1];
    float4 xv = *reinterpret_cast<const float4*>(&xst[d * 4]);
    acc[0][0] += xv.x * w0; acc[0][1] += xv.x * w1;
    acc[1][0] += xv.y * w0; acc[1][1] += xv.y * w1;
    acc[2][0] += xv.z * w0; acc[2][1] += xv.z * w1;
    acc[3][0] += xv.w * w0; acc[3][1] += xv.w * w1;
  }
  float bb0 = b1[j0], bb1 = b1[j1];
#pragma unroll
  for (int r = 0; r < 4; ++r)
    xw1[(size_t)(row0 + r) * 256 + tid] = packh2(acc[r][0] + bb0, acc[r][1] + bb1);
}

// ---------- persistent pipelined 2-layer recurrence ----------
// grid 256: WG 0..127 = layer1 (16 groups x 8 slices), 128..255 = layer2.
// Each WG: NB=2 batches, 64 cols, 8 waves (wave = K-range), weights in VGPRs.
// Exchange: sentinel-flagged packed-f16 words in rings (agent-scope u32).
__global__ __launch_bounds__(512, 2) void k_rnn(
    const unsigned* __restrict__ xw1,     // [T*B][256]
    const float* __restrict__ Wh1,
    const float* __restrict__ Wx2, const float* __restrict__ Wh2,
    const float* __restrict__ b2,
    unsigned* __restrict__ ringA,         // L1 self   [RING][B][256]
    unsigned* __restrict__ ringB,         // L1 -> L2  [RING][B][256]
    unsigned* __restrict__ ringC,         // L2 self   [RING][B][256]
    int* __restrict__ prog2,              // [NGRP][NSL] L2 progress
    float* __restrict__ h2fin)            // [B][H]
{
  const int tid  = threadIdx.x;
  const int wgid = blockIdx.x;
  const int layer = wgid >> 7;
  const int lw = wgid & 127;
  const int g  = lw >> 3, sl = lw & 7;
  const int b0 = g * NB;
  const int c0 = sl * 64;
  const int w  = tid >> 6, j = tid & 63;
  const int col = c0 + j;

  __shared__ __align__(16) unsigned h_s[NB][512];
  __shared__ float red[8][NB][64];

  if (layer == 0) {
    // ================= LAYER 1 (K=512) =================
    const int kw = w * 32;                 // word offset into 256-word h vec
    unsigned wreg[32];
    {
      const int k0 = w * 64;
#pragma unroll
      for (int i = 0; i < 32; ++i) {
        float a = Wh1[(size_t)(k0 + 2 * i) * HID + col];
        float b = Wh1[(size_t)(k0 + 2 * i + 1) * HID + col];
        wreg[i] = packh2(a, b);
      }
    }
    int cached = -1;
    const int pb = tid >> 8;               // poll batch 0/1
    const int pw = tid & 255;              // poll word
    for (int t = 0; t < TLEN; ++t) {
      // prefetch xw word (used in final phase)
      unsigned xww = 0;
      if (tid < 128) {
        int bb = tid >> 6, jj = tid & 63;
        xww = xw1[((size_t)t * BATCH + b0 + bb) * 256 + ((c0 + jj) >> 1)];
      }
      // flow control vs L2 before touching ringB (waves 0,1 do the stores)
      if (w < 2) {
        int need = t - (RING - 6);
        if (cached < need) {
          unsigned it = 0;
          for (;;) {
            int p = (j < NSL) ? aloadi(&prog2[g * NSL + j]) : 0x7fffffff;
#pragma unroll
            for (int d = 1; d < NSL; d <<= 1) p = min(p, __shfl_xor(p, d));
            p = __shfl(p, 0);
            cached = p;
            if (cached >= need || ++it >= POLL_CAP) break;
          }
        }
      }
      // poll h1[t-1]
      {
        unsigned v = 0;
        if (t > 0) {
          const unsigned* p =
              &ringA[((size_t)((t - 1) & (RING - 1)) * BATCH + b0 + pb) * 256 + pw];
          unsigned it = 0;
          do { v = aload(p); } while (v == SENTV && ++it < POLL_CAP);
          if (v == SENTV) v = 0;
        }
        h_s[pb][pw] = v;
      }
      // reset own words in slot t+1 (holds step t-31; consumers proven done)
      if (tid < 64) {
        int bb = tid >> 5, wi = (c0 >> 1) + (tid & 31);
        size_t off = ((size_t)((t + 1) & (RING - 1)) * BATCH + b0 + bb) * 256 + wi;
        astore(&ringA[off], SENTV);
        astore(&ringB[off], SENTV);
      }
      __syncthreads();                      // B1: h_s ready, resets drained
      float acc0 = 0.f, acc1 = 0.f;
#pragma unroll
      for (int i = 0; i < 8; ++i) {
        uint4 ha = *reinterpret_cast<const uint4*>(&h_s[0][kw + 4 * i]);
        uint4 hb = *reinterpret_cast<const uint4*>(&h_s[1][kw + 4 * i]);
        acc0 = fdot2u(ha.x, wreg[4 * i + 0], acc0);
        acc0 = fdot2u(ha.y, wreg[4 * i + 1], acc0);
        acc0 = fdot2u(ha.z, wreg[4 * i + 2], acc0);
        acc0 = fdot2u(ha.w, wreg[4 * i + 3], acc0);
        acc1 = fdot2u(hb.x, wreg[4 * i + 0], acc1);
        acc1 = fdot2u(hb.y, wreg[4 * i + 1], acc1);
        acc1 = fdot2u(hb.z, wreg[4 * i + 2], acc1);
        acc1 = fdot2u(hb.w, wreg[4 * i + 3], acc1);
      }
      red[w][0][j] = acc0;
      red[w][1][j] = acc1;
      __syncthreads();                      // B2
      if (tid < 128) {
        int bb = tid >> 6, jj = tid & 63;
        hf2 xv = __builtin_bit_cast(hf2, xww);
        float z = (float)xv[jj & 1];
#pragma unroll
        for (int r = 0; r < 8; ++r) z += red[r][bb][jj];
        float h = tanhf(z);
        float hn = __shfl_down(h, 1);
        if ((jj & 1) == 0) {
          unsigned u = packh2(h, hn);
          size_t off = ((size_t)(t & (RING - 1)) * BATCH + b0 + bb) * 256 + ((c0 + jj) >> 1);
          astore(&ringA[off], u);
          astore(&ringB[off], u);
        }
      }
    }
  } else {
    // ================= LAYER 2 (K=1024: [h1;h2] @ [Wx2;Wh2]) =================
    const int kw = w * 64;                 // word offset into 512-word combined vec
    unsigned wreg[64];
    {
      const int k0 = w * 128;
#pragma unroll
      for (int i = 0; i < 64; ++i) {
        int k = k0 + 2 * i;
        float a, b;
        if (k < HID) {
          a = Wx2[(size_t)k * HID + col];
          b = Wx2[(size_t)(k + 1) * HID + col];
        } else {
          a = Wh2[(size_t)(k - HID) * HID + col];
          b = Wh2[(size_t)(k - HID + 1) * HID + col];
        }
        wreg[i] = packh2(a, b);
      }
    }
    float b2v = 0.f;
    if (tid < 128) b2v = b2[c0 + (tid & 63)];
    for (int t = 0; t < TLEN; ++t) {
      // poll: word tid for both batches (tid<256: h1[t] from ringB; else h2[t-1] from ringC)
      {
        const unsigned* p0 = nullptr; const unsigned* p1 = nullptr;
        unsigned v0 = 0, v1 = 0;
        if (tid < 256) {
          size_t base = ((size_t)(t & (RING - 1)) * BATCH + b0) * 256 + tid;
          p0 = &ringB[base]; p1 = &ringB[base + 256];
          v0 = SENTV; v1 = SENTV;
        } else if (t > 0) {
          size_t base = ((size_t)((t - 1) & (RING - 1)) * BATCH + b0) * 256 + (tid - 256);
          p0 = &ringC[base]; p1 = &ringC[base + 256];
          v0 = SENTV; v1 = SENTV;
        }
        if (p0) {
          unsigned it = 0;
          while ((v0 == SENTV || v1 == SENTV) && it < POLL_CAP) {
            if (v0 == SENTV) v0 = aload(p0);
            if (v1 == SENTV) v1 = aload(p1);
            ++it;
          }
          if (v0 == SENTV) v0 = 0;
          if (v1 == SENTV) v1 = 0;
        }
        h_s[0][tid] = v0;
        h_s[1][tid] = v1;
      }
      // reset own ringC words in slot t+1
      if (tid < 64) {
        int bb = tid >> 5, wi = (c0 >> 1) + (tid & 31);
        astore(&ringC[((size_t)((t + 1) & (RING - 1)) * BATCH + b0 + bb) * 256 + wi], SENTV);
      }
      __syncthreads();                      // B1
      if (tid == 0) astorei(&prog2[g * NSL + sl], t);   // consumed h1[t]
      float acc0 = 0.f, acc1 = 0.f;
#pragma unroll
      for (int i = 0; i < 16; ++i) {
        uint4 ha = *reinterpret_cast<const uint4*>(&h_s[0][kw + 4 * i]);
        uint4 hb = *reinterpret_cast<const uint4*>(&h_s[1][kw + 4 * i]);
        acc0 = fdot2u(ha.x, wreg[4 * i + 0], acc0);
        acc0 = fdot2u(ha.y, wreg[4 * i + 1], acc0);
        acc0 = fdot2u(ha.z, wreg[4 * i + 2], acc0);
        acc0 = fdot2u(ha.w, wreg[4 * i + 3], acc0);
        acc1 = fdot2u(hb.x, wreg[4 * i + 0], acc1);
        acc1 = fdot2u(hb.y, wreg[4 * i + 1], acc1);
        acc1 = fdot2u(hb.z, wreg[4 * i + 2], acc1);
        acc1 = fdot2u(hb.w, wreg[4 * i + 3], acc1);
      }
      red[w][0][j] = acc0;
      red[w][1][j] = acc1;
      __syncthreads();                      // B2
      if (tid < 128) {
        int bb = tid >> 6, jj = tid & 63;
        float z = b2v;
#pragma unroll
        for (int r = 0; r < 8; ++r) z += red[r][bb][jj];
        float h = tanhf(z);
        if (t == TLEN - 1) h2fin[(size_t)(b0 + bb) * HID + c0 + jj] = h;
        float hn = __shfl_down(h, 1);
        if ((jj & 1) == 0) {
          astore(&ringC[((size_t)(t & (RING - 1)) * BATCH + b0 + bb) * 256 + ((c0 + jj) >> 1)],
                 packh2(h, hn));
        }
      }
    }
  }
}

// ---------- softmax(h2 @ Wo + bo) ----------
__global__ __launch_bounds__(640) void k_head(
    const float* __restrict__ h2, const float* __restrict__ Wo,
    const float* __restrict__ bo, float* __restrict__ out)
{
  __shared__ float lg[16];
  const int b = blockIdx.x;
  const int c = threadIdx.x >> 6;   // wave per class
  const int l = threadIdx.x & 63;
  float p = 0.f;
#pragma unroll
  for (int i = 0; i < 8; ++i) {
    int k = l + 64 * i;
    p += h2[(size_t)b * HID + k] * Wo[(size_t)k * NCLS + c];
  }
  for (int off = 32; off; off >>= 1) p += __shfl_down(p, off);
  if (l == 0) lg[c] = p + bo[c];
  __syncthreads();
  if (threadIdx.x == 0) {
    float m = lg[0];
    for (int i = 1; i < NCLS; ++i) m = fmaxf(m, lg[i]);
    float e[NCLS];
    float s = 0.f;
    for (int i = 0; i < NCLS; ++i) { e[i] = expf(lg[i] - m); s += e[i]; }
    for (int i = 0; i < NCLS; ++i) out[(size_t)b * NCLS + i] = e[i] / s;
  }
}

extern "C" void kernel_launch(void* const* d_in, const int* in_sizes, int n_in,
                              void* d_out, int out_size, void* d_ws, size_t ws_size,
                              hipStream_t stream)
{
  (void)in_sizes; (void)n_in; (void)out_size; (void)ws_size;
  const float* x   = (const float*)d_in[0];
  const float* Wx1 = (const float*)d_in[1];
  const float* Wh1 = (const float*)d_in[2];
  const float* b1  = (const float*)d_in[3];
  const float* Wx2 = (const float*)d_in[4];
  const float* Wh2 = (const float*)d_in[5];
  const float* b2  = (const float*)d_in[6];
  const float* Wo  = (const float*)d_in[7];
  const float* bo  = (const float*)d_in[8];
  float* out = (float*)d_out;

  char* ws = (char*)d_ws;
  size_t o = 0;
  unsigned* xw1 = (unsigned*)(ws + o); o += (size_t)TLEN * BATCH * 256 * 4;  // 32MB
  const size_t ringBytes = (size_t)RING * BATCH * 256 * 4;                   // 1MB
  unsigned* ringA = (unsigned*)(ws + o); o += ringBytes;
  unsigned* ringB = (unsigned*)(ws + o); o += ringBytes;
  unsigned* ringC = (unsigned*)(ws + o); o += ringBytes;
  int* prog2 = (int*)(ws + o); o += 1024;
  float* h2fin = (float*)(ws + o); o += (size_t)BATCH * HID * 4;

  hipMemsetAsync(ringA, 0xFF, 3 * ringBytes, stream);   // A,B,C contiguous
  hipMemsetAsync(prog2, 0xFF, NGRP * NSL * 4, stream);

  k_xw1<<<TLEN * BATCH / 4, 256, 0, stream>>>(x, Wx1, b1, xw1);
  k_rnn<<<256, 512, 0, stream>>>(xw1, Wh1, Wx2, Wh2, b2,
                                 ringA, ringB, ringC, prog2, h2fin);
  k_head<<<BATCH, 640, 0, stream>>>(h2fin, Wo, bo, out);
}

// Round 3
// 2354.924 us; speedup vs baseline: 5.3163x; 1.0383x over previous
//
#include <hip/hip_runtime.h>
#include <hip/hip_fp16.h>
#include <math.h>

#define BATCH 32
#define TLEN  1024
#define DIN   128
#define HID   512
#define NCLS  10
#define NB    2                 // batches per WG
#define NGRP  (BATCH/NB)        // 16 groups
#define NSL   8                 // slice WGs per group per layer (64 cols each)
#define RING  32                // ring depth (slots)
#define SENTV 0xFFFFFFFFu
#define POLL_CAP (1u<<17)

typedef _Float16 hf2 __attribute__((ext_vector_type(2)));

__device__ __forceinline__ unsigned aload(const unsigned* p) {
  return __hip_atomic_load(p, __ATOMIC_RELAXED, __HIP_MEMORY_SCOPE_AGENT);
}
__device__ __forceinline__ void astore(unsigned* p, unsigned v) {
  __hip_atomic_store(p, v, __ATOMIC_RELAXED, __HIP_MEMORY_SCOPE_AGENT);
}
__device__ __forceinline__ int aloadi(const int* p) {
  return __hip_atomic_load(p, __ATOMIC_RELAXED, __HIP_MEMORY_SCOPE_AGENT);
}
__device__ __forceinline__ void astorei(int* p, int v) {
  __hip_atomic_store(p, v, __ATOMIC_RELAXED, __HIP_MEMORY_SCOPE_AGENT);
}

__device__ __forceinline__ float fdot2u(unsigned a, unsigned b, float c) {
#if __has_builtin(__builtin_amdgcn_fdot2)
  return __builtin_amdgcn_fdot2(__builtin_bit_cast(hf2, a),
                                __builtin_bit_cast(hf2, b), c, false);
#else
  hf2 av = __builtin_bit_cast(hf2, a), bv = __builtin_bit_cast(hf2, b);
  return c + (float)av[0] * (float)bv[0] + (float)av[1] * (float)bv[1];
#endif
}

__device__ __forceinline__ unsigned packh2(float lo, float hi) {
  __half2 h = __floats2half2_rn(lo, hi);
  return __builtin_bit_cast(unsigned, h);
}

// ---------- xw1[t,b,:] = x[b,t,:] @ Wx1 + b1, packed f16 pairs, all T ----------
__global__ __launch_bounds__(256) void k_xw1(
    const float* __restrict__ x, const float* __restrict__ Wx1,
    const float* __restrict__ b1, unsigned* __restrict__ xw1)   // [T*B][256] words
{
  __shared__ float xst[DIN * 4];
  const int tid  = threadIdx.x;
  const int row0 = blockIdx.x * 4;            // row = t*32 + b
  for (int idx = tid; idx < 4 * DIN; idx += 256) {
    int r = idx >> 7, d = idx & (DIN - 1);
    int row = row0 + r;
    int t = row >> 5, b = row & 31;
    xst[d * 4 + r] = x[((size_t)b * TLEN + t) * DIN + d];
  }
  __syncthreads();
  float acc[4][2];
#pragma unroll
  for (int r = 0; r < 4; ++r) { acc[r][0] = 0.f; acc[r][1] = 0.f; }
  const int j0 = 2 * tid, j1 = 2 * tid + 1;
  for (int d = 0; d < DIN; ++d) {
    float w0 = Wx1[(size_t)d * HID + j0];
    float w1 = Wx1[(size_t)d * HID + j1];
    float4 xv = *reinterpret_cast<const float4*>(&xst[d * 4]);
    acc[0][0] += xv.x * w0; acc[0][1] += xv.x * w1;
    acc[1][0] += xv.y * w0; acc[1][1] += xv.y * w1;
    acc[2][0] += xv.z * w0; acc[2][1] += xv.z * w1;
    acc[3][0] += xv.w * w0; acc[3][1] += xv.w * w1;
  }
  float bb0 = b1[j0], bb1 = b1[j1];
#pragma unroll
  for (int r = 0; r < 4; ++r)
    xw1[(size_t)(row0 + r) * 256 + tid] = packh2(acc[r][0] + bb0, acc[r][1] + bb1);
}

// ---------- persistent pipelined 2-layer recurrence ----------
// grid 256 x 512 threads: WG 0..127 = layer1, 128..255 = layer2.
// WG handles NB=2 batches x 64 cols. Within a wave: lane = q*16 + lo,
// q = K-quarter, lo -> output o = w*16+lo (o>>6 = batch, o&63 = col).
// One barrier per step; parity-double-buffered h_s; sentinel-flagged rings.
__global__ __launch_bounds__(512) void k_rnn(
    const unsigned* __restrict__ xw1,     // [T*B][256]
    const float* __restrict__ Wh1,
    const float* __restrict__ Wx2, const float* __restrict__ Wh2,
    const float* __restrict__ b2,
    unsigned* __restrict__ ring1,         // [RING][B][256]: L1 h (peers t-1, L2 t)
    unsigned* __restrict__ ringC,         // [RING][B][256]: L2 self
    int* __restrict__ prog2,              // [NGRP][NSL] L2 progress
    float* __restrict__ h2fin)            // [B][H]
{
  const int tid  = threadIdx.x;
  const int wgid = blockIdx.x;
  const int layer = wgid >> 7;
  const int lw = wgid & 127;
  const int g  = lw >> 3, sl = lw & 7;
  const int b0 = g * NB;
  const int c0 = sl * 64;
  const int w  = tid >> 6, l = tid & 63;
  const int q  = l >> 4;                 // K-quarter
  const int lo = l & 15;
  const int o  = w * 16 + lo;            // 0..127
  const int obb = o >> 6, oj = o & 63;
  const int ocol = c0 + oj;

  const int pw = tid & 255;              // poll word
  const int pb = tid >> 8;               // poll batch

  __shared__ __align__(16) unsigned h_s[2][NB][512];  // [parity][batch][word]

  if (layer == 0) {
    // ================= LAYER 1 (K=512) =================
    unsigned wreg[64];
    {
      const int k0 = q * 128;
#pragma unroll
      for (int i = 0; i < 64; ++i) {
        float a = Wh1[(size_t)(k0 + 2 * i) * HID + ocol];
        float b = Wh1[(size_t)(k0 + 2 * i + 1) * HID + ocol];
        wreg[i] = packh2(a, b);
      }
    }
    int cached = -1;
    for (int t = 0; t < TLEN; ++t) {
      const int p = t & 1;
      // xw prefetch (q0 lanes use it in finalize)
      unsigned xww = 0;
      if (q == 0)
        xww = xw1[((size_t)t * BATCH + b0 + obb) * 256 + (ocol >> 1)];
      // wave 0: throttle L2 lag, then reset slot t+1 (holds step t-31)
      if (w == 0) {
        const int need = t - (RING - 6);
        if (cached < need) {
          unsigned it = 0;
          for (;;) {
            int pr = (l < NSL) ? aloadi(&prog2[g * NSL + l]) : 0x7fffffff;
#pragma unroll
            for (int d = 1; d < NSL; d <<= 1) pr = min(pr, __shfl_xor(pr, d));
            pr = __shfl(pr, 0);
            cached = pr;
            if (cached >= need || ++it >= POLL_CAP) break;
          }
        }
        int rb = l >> 5, rw = (c0 >> 1) + (l & 31);
        astore(&ring1[((size_t)((t + 1) & (RING - 1)) * BATCH + b0 + rb) * 256 + rw], SENTV);
      }
      // poll h(t-1)
      {
        unsigned v = 0;
        if (t > 0) {
          const unsigned* pp =
              &ring1[((size_t)((t - 1) & (RING - 1)) * BATCH + b0 + pb) * 256 + pw];
          unsigned it = 0;
          do { v = aload(pp); } while (v == SENTV && ++it < POLL_CAP);
          if (v == SENTV) v = 0;
        }
        h_s[p][pb][pw] = v;
      }
      __syncthreads();   // h_s[p] ready; wave-0 resets drained
      float acc = 0.f;
      const unsigned* hp = &h_s[p][obb][q * 64];
#pragma unroll
      for (int i = 0; i < 16; ++i) {
        uint4 hv = *reinterpret_cast<const uint4*>(&hp[4 * i]);
        acc = fdot2u(hv.x, wreg[4 * i + 0], acc);
        acc = fdot2u(hv.y, wreg[4 * i + 1], acc);
        acc = fdot2u(hv.z, wreg[4 * i + 2], acc);
        acc = fdot2u(hv.w, wreg[4 * i + 3], acc);
      }
      acc += __shfl_xor(acc, 16);
      acc += __shfl_xor(acc, 32);
      if (q == 0) {
        hf2 xv = __builtin_bit_cast(hf2, xww);
        float z = (float)xv[oj & 1] + acc;
        float h = tanhf(z);
        float hn = __shfl_down(h, 1);
        if (!(lo & 1))
          astore(&ring1[((size_t)(t & (RING - 1)) * BATCH + b0 + obb) * 256 + (ocol >> 1)],
                 packh2(h, hn));
      }
    }
  } else {
    // ================= LAYER 2 (K=1024: [h1(t); h2(t-1)] @ [Wx2;Wh2]) =========
    unsigned wreg[128];
    {
      const int k0 = q * 256;
#pragma unroll
      for (int i = 0; i < 128; ++i) {
        int k = k0 + 2 * i;
        float a, b;
        if (k < HID) {
          a = Wx2[(size_t)k * HID + ocol];
          b = Wx2[(size_t)(k + 1) * HID + ocol];
        } else {
          a = Wh2[(size_t)(k - HID) * HID + ocol];
          b = Wh2[(size_t)(k - HID + 1) * HID + ocol];
        }
        wreg[i] = packh2(a, b);
      }
    }
    float b2v = (q == 0) ? b2[ocol] : 0.f;
    for (int t = 0; t < TLEN; ++t) {
      const int p = t & 1;
      // poll h1(t) from ring1 slot t, h2(t-1) from ringC slot t-1
      {
        const unsigned* p0 =
            &ring1[((size_t)(t & (RING - 1)) * BATCH + b0 + pb) * 256 + pw];
        unsigned v0 = SENTV, v1 = SENTV;
        const unsigned* p1 = nullptr;
        if (t > 0)
          p1 = &ringC[((size_t)((t - 1) & (RING - 1)) * BATCH + b0 + pb) * 256 + pw];
        else
          v1 = 0;
        unsigned it = 0;
        while ((v0 == SENTV || v1 == SENTV) && it < POLL_CAP) {
          if (v0 == SENTV) v0 = aload(p0);
          if (v1 == SENTV && p1) v1 = aload(p1);
          ++it;
        }
        if (v0 == SENTV) v0 = 0;
        if (v1 == SENTV) v1 = 0;
        h_s[p][pb][pw] = v0;
        h_s[p][pb][256 + pw] = v1;
      }
      // wave 0: reset ringC slot t+1
      if (w == 0) {
        int rb = l >> 5, rw = (c0 >> 1) + (l & 31);
        astore(&ringC[((size_t)((t + 1) & (RING - 1)) * BATCH + b0 + rb) * 256 + rw], SENTV);
      }
      __syncthreads();
      if (tid == 0) astorei(&prog2[g * NSL + sl], t);   // consumed ring1 slot t
      float acc = 0.f;
      const unsigned* hp = &h_s[p][obb][q * 128];
#pragma unroll
      for (int i = 0; i < 32; ++i) {
        uint4 hv = *reinterpret_cast<const uint4*>(&hp[4 * i]);
        acc = fdot2u(hv.x, wreg[4 * i + 0], acc);
        acc = fdot2u(hv.y, wreg[4 * i + 1], acc);
        acc = fdot2u(hv.z, wreg[4 * i + 2], acc);
        acc = fdot2u(hv.w, wreg[4 * i + 3], acc);
      }
      acc += __shfl_xor(acc, 16);
      acc += __shfl_xor(acc, 32);
      if (q == 0) {
        float z = b2v + acc;
        float h = tanhf(z);
        if (t == TLEN - 1) h2fin[(size_t)(b0 + obb) * HID + ocol] = h;
        float hn = __shfl_down(h, 1);
        if (!(lo & 1))
          astore(&ringC[((size_t)(t & (RING - 1)) * BATCH + b0 + obb) * 256 + (ocol >> 1)],
                 packh2(h, hn));
      }
    }
  }
}

// ---------- softmax(h2 @ Wo + bo) ----------
__global__ __launch_bounds__(640) void k_head(
    const float* __restrict__ h2, const float* __restrict__ Wo,
    const float* __restrict__ bo, float* __restrict__ out)
{
  __shared__ float lg[16];
  const int b = blockIdx.x;
  const int c = threadIdx.x >> 6;   // wave per class
  const int l = threadIdx.x & 63;
  float p = 0.f;
#pragma unroll
  for (int i = 0; i < 8; ++i) {
    int k = l + 64 * i;
    p += h2[(size_t)b * HID + k] * Wo[(size_t)k * NCLS + c];
  }
  for (int off = 32; off; off >>= 1) p += __shfl_down(p, off);
  if (l == 0) lg[c] = p + bo[c];
  __syncthreads();
  if (threadIdx.x == 0) {
    float m = lg[0];
    for (int i = 1; i < NCLS; ++i) m = fmaxf(m, lg[i]);
    float e[NCLS];
    float s = 0.f;
    for (int i = 0; i < NCLS; ++i) { e[i] = expf(lg[i] - m); s += e[i]; }
    for (int i = 0; i < NCLS; ++i) out[(size_t)b * NCLS + i] = e[i] / s;
  }
}

extern "C" void kernel_launch(void* const* d_in, const int* in_sizes, int n_in,
                              void* d_out, int out_size, void* d_ws, size_t ws_size,
                              hipStream_t stream)
{
  (void)in_sizes; (void)n_in; (void)out_size; (void)ws_size;
  const float* x   = (const float*)d_in[0];
  const float* Wx1 = (const float*)d_in[1];
  const float* Wh1 = (const float*)d_in[2];
  const float* b1  = (const float*)d_in[3];
  const float* Wx2 = (const float*)d_in[4];
  const float* Wh2 = (const float*)d_in[5];
  const float* b2  = (const float*)d_in[6];
  const float* Wo  = (const float*)d_in[7];
  const float* bo  = (const float*)d_in[8];
  float* out = (float*)d_out;

  char* ws = (char*)d_ws;
  size_t o = 0;
  unsigned* xw1 = (unsigned*)(ws + o); o += (size_t)TLEN * BATCH * 256 * 4;  // 32MB
  const size_t ringBytes = (size_t)RING * BATCH * 256 * 4;                   // 1MB
  unsigned* ring1 = (unsigned*)(ws + o); o += ringBytes;
  unsigned* ringC = (unsigned*)(ws + o); o += ringBytes;
  int* prog2 = (int*)(ws + o); o += 1024;
  float* h2fin = (float*)(ws + o); o += (size_t)BATCH * HID * 4;

  hipMemsetAsync(ring1, 0xFF, 2 * ringBytes, stream);   // ring1, ringC contiguous
  hipMemsetAsync(prog2, 0xFF, NGRP * NSL * 4, stream);

  k_xw1<<<TLEN * BATCH / 4, 256, 0, stream>>>(x, Wx1, b1, xw1);
  k_rnn<<<256, 512, 0, stream>>>(xw1, Wh1, Wx2, Wh2, b2,
                                 ring1, ringC, prog2, h2fin);
  k_head<<<BATCH, 640, 0, stream>>>(h2fin, Wo, bo, out);
}